// Round 1
// baseline (269.525 us; speedup 1.0000x reference)
//
#include <hip/hip_runtime.h>
#include <math.h>

#define IN_F   8192
#define OUT_F  8192
#define CAT    16384
#define BLOCK  256

// float4 granularity: CAT/4 = 4096 float4 per row; 4096/256 = 16 per thread.
// First 2048 float4 of a row pair with x, last 2048 with prediction.
#define F4_HALF (IN_F / 4)   // 2048

__global__ __launch_bounds__(BLOCK) void lstm_fused_kernel(
    const float* __restrict__ x,
    const float* __restrict__ prediction,
    const float* __restrict__ hidden_state,
    const float* __restrict__ W_f, const float* __restrict__ b_f,
    const float* __restrict__ W_i, const float* __restrict__ b_i,
    const float* __restrict__ W_o, const float* __restrict__ b_o,
    float* __restrict__ out)
{
    const int row = blockIdx.x;
    const int t   = threadIdx.x;

    const float4* Wf4 = (const float4*)(W_f + (size_t)row * CAT);
    const float4* Wi4 = (const float4*)(W_i + (size_t)row * CAT);
    const float4* Wo4 = (const float4*)(W_o + (size_t)row * CAT);
    const float4* x4  = (const float4*)x;
    const float4* p4  = (const float4*)prediction;

    float accF = 0.f, accI = 0.f, accO = 0.f;

    // First half of the row: pairs with x
#pragma unroll
    for (int k = 0; k < 8; ++k) {
        const int c = t + k * BLOCK;          // [0, 2048)
        const float4 v  = x4[c];
        const float4 wf = Wf4[c];
        const float4 wi = Wi4[c];
        const float4 wo = Wo4[c];
        accF += wf.x * v.x + wf.y * v.y + wf.z * v.z + wf.w * v.w;
        accI += wi.x * v.x + wi.y * v.y + wi.z * v.z + wi.w * v.w;
        accO += wo.x * v.x + wo.y * v.y + wo.z * v.z + wo.w * v.w;
    }
    // Second half of the row: pairs with prediction
#pragma unroll
    for (int k = 8; k < 16; ++k) {
        const int c = t + k * BLOCK;          // [2048, 4096)
        const float4 v  = p4[c - F4_HALF];
        const float4 wf = Wf4[c];
        const float4 wi = Wi4[c];
        const float4 wo = Wo4[c];
        accF += wf.x * v.x + wf.y * v.y + wf.z * v.z + wf.w * v.w;
        accI += wi.x * v.x + wi.y * v.y + wi.z * v.z + wi.w * v.w;
        accO += wo.x * v.x + wo.y * v.y + wo.z * v.z + wo.w * v.w;
    }

    // Wave-level butterfly reduce (64 lanes)
#pragma unroll
    for (int off = 32; off > 0; off >>= 1) {
        accF += __shfl_down(accF, off);
        accI += __shfl_down(accI, off);
        accO += __shfl_down(accO, off);
    }

    __shared__ float sF[4], sI[4], sO[4];
    const int wave = t >> 6;
    const int lane = t & 63;
    if (lane == 0) { sF[wave] = accF; sI[wave] = accI; sO[wave] = accO; }
    __syncthreads();

    if (t == 0) {
        const float F = sF[0] + sF[1] + sF[2] + sF[3] + b_f[row];
        const float I = sI[0] + sI[1] + sI[2] + sI[3] + b_i[row];
        const float O = sO[0] + sO[1] + sO[2] + sO[3] + b_o[row];

        const float fg = 1.f / (1.f + expf(-F));
        const float ig = tanhf(I) * (1.f / (1.f + expf(-I)));
        const float og = 1.f / (1.f + expf(-O));

        const float h = fg * hidden_state[row] + ig;
        out[row] = og * fmaxf(h, 0.f);
    }
}

extern "C" void kernel_launch(void* const* d_in, const int* in_sizes, int n_in,
                              void* d_out, int out_size, void* d_ws, size_t ws_size,
                              hipStream_t stream) {
    // setup_inputs order:
    // 0:x 1:prediction 2:hidden_state 3:W_f 4:b_f 5:W_i 6:b_i 7:W_bi 8:b_bi 9:W_o 10:b_o
    const float* x           = (const float*)d_in[0];
    const float* prediction  = (const float*)d_in[1];
    const float* hidden      = (const float*)d_in[2];
    const float* W_f         = (const float*)d_in[3];
    const float* b_f         = (const float*)d_in[4];
    const float* W_i         = (const float*)d_in[5];
    const float* b_i         = (const float*)d_in[6];
    // d_in[7] = W_bi, d_in[8] = b_bi — dead code in the reference, never read.
    const float* W_o         = (const float*)d_in[9];
    const float* b_o         = (const float*)d_in[10];
    float* out               = (float*)d_out;

    lstm_fused_kernel<<<OUT_F, BLOCK, 0, stream>>>(
        x, prediction, hidden, W_f, b_f, W_i, b_i, W_o, b_o, out);
}

// Round 2
// 228.507 us; speedup vs baseline: 1.1795x; 1.1795x over previous
//
#include <hip/hip_runtime.h>
#include <math.h>

#define IN_F   8192
#define OUT_F  8192
#define CAT    16384
#define BLOCK  256

// float4 granularity: CAT/4 = 4096 float4 per row; 4096/256 = 16 per thread.
#define F4_HALF (IN_F / 4)   // 2048

// ext_vector float4 so __builtin_nontemporal_load accepts it
typedef float f4 __attribute__((ext_vector_type(4)));

__global__ __launch_bounds__(BLOCK) void lstm_fused_kernel(
    const float* __restrict__ x,
    const float* __restrict__ prediction,
    const float* __restrict__ hidden_state,
    const float* __restrict__ W_f, const float* __restrict__ b_f,
    const float* __restrict__ W_i, const float* __restrict__ b_i,
    const float* __restrict__ W_o, const float* __restrict__ b_o,
    float* __restrict__ out)
{
    const int row = blockIdx.x;
    const int t   = threadIdx.x;

    const f4* Wf4 = (const f4*)(W_f + (size_t)row * CAT);
    const f4* Wi4 = (const f4*)(W_i + (size_t)row * CAT);
    const f4* Wo4 = (const f4*)(W_o + (size_t)row * CAT);
    const f4* x4  = (const f4*)x;
    const f4* p4  = (const f4*)prediction;

    float accF = 0.f, accI = 0.f, accO = 0.f;

    // First half of the row: pairs with x (x/p stay cacheable; weights are
    // single-use -> nontemporal so they don't thrash L2/L3).
#pragma unroll
    for (int k = 0; k < 8; ++k) {
        const int c = t + k * BLOCK;          // [0, 2048)
        const f4 v  = x4[c];
        const f4 wf = __builtin_nontemporal_load(Wf4 + c);
        const f4 wi = __builtin_nontemporal_load(Wi4 + c);
        const f4 wo = __builtin_nontemporal_load(Wo4 + c);
        accF += wf.x * v.x + wf.y * v.y + wf.z * v.z + wf.w * v.w;
        accI += wi.x * v.x + wi.y * v.y + wi.z * v.z + wi.w * v.w;
        accO += wo.x * v.x + wo.y * v.y + wo.z * v.z + wo.w * v.w;
    }
    // Second half of the row: pairs with prediction
#pragma unroll
    for (int k = 8; k < 16; ++k) {
        const int c = t + k * BLOCK;          // [2048, 4096)
        const f4 v  = p4[c - F4_HALF];
        const f4 wf = __builtin_nontemporal_load(Wf4 + c);
        const f4 wi = __builtin_nontemporal_load(Wi4 + c);
        const f4 wo = __builtin_nontemporal_load(Wo4 + c);
        accF += wf.x * v.x + wf.y * v.y + wf.z * v.z + wf.w * v.w;
        accI += wi.x * v.x + wi.y * v.y + wi.z * v.z + wi.w * v.w;
        accO += wo.x * v.x + wo.y * v.y + wo.z * v.z + wo.w * v.w;
    }

    // Wave-level butterfly reduce (64 lanes)
#pragma unroll
    for (int off = 32; off > 0; off >>= 1) {
        accF += __shfl_down(accF, off);
        accI += __shfl_down(accI, off);
        accO += __shfl_down(accO, off);
    }

    __shared__ float sF[4], sI[4], sO[4];
    const int wave = t >> 6;
    const int lane = t & 63;
    if (lane == 0) { sF[wave] = accF; sI[wave] = accI; sO[wave] = accO; }
    __syncthreads();

    if (t == 0) {
        const float F = sF[0] + sF[1] + sF[2] + sF[3] + b_f[row];
        const float I = sI[0] + sI[1] + sI[2] + sI[3] + b_i[row];
        const float O = sO[0] + sO[1] + sO[2] + sO[3] + b_o[row];

        const float fg = 1.f / (1.f + expf(-F));
        const float ig = tanhf(I) * (1.f / (1.f + expf(-I)));
        const float og = 1.f / (1.f + expf(-O));

        const float h = fg * hidden_state[row] + ig;
        out[row] = og * fmaxf(h, 0.f);
    }
}

extern "C" void kernel_launch(void* const* d_in, const int* in_sizes, int n_in,
                              void* d_out, int out_size, void* d_ws, size_t ws_size,
                              hipStream_t stream) {
    // setup_inputs order:
    // 0:x 1:prediction 2:hidden_state 3:W_f 4:b_f 5:W_i 6:b_i 7:W_bi 8:b_bi 9:W_o 10:b_o
    const float* x           = (const float*)d_in[0];
    const float* prediction  = (const float*)d_in[1];
    const float* hidden      = (const float*)d_in[2];
    const float* W_f         = (const float*)d_in[3];
    const float* b_f         = (const float*)d_in[4];
    const float* W_i         = (const float*)d_in[5];
    const float* b_i         = (const float*)d_in[6];
    // d_in[7] = W_bi, d_in[8] = b_bi — dead code in the reference, never read.
    const float* W_o         = (const float*)d_in[9];
    const float* b_o         = (const float*)d_in[10];
    float* out               = (float*)d_out;

    lstm_fused_kernel<<<OUT_F, BLOCK, 0, stream>>>(
        x, prediction, hidden, W_f, b_f, W_i, b_i, W_o, b_o, out);
}